// Round 2
// baseline (4047.375 us; speedup 1.0000x reference)
//
#include <hip/hip_runtime.h>
#include <hip/hip_bf16.h>
#include <cstdint>
#include <cstddef>

// LSTM encoder: T=256, B=64, VOCAB=32000, E=512, H=1024
#define T_STEPS 256
#define BATCH   64
#define DE      512
#define DH      1024
#define G4      4096   // 4*DH

typedef short  bf16x8 __attribute__((ext_vector_type(8)));   // 8 bf16 = 4 VGPRs
typedef float  f32x4  __attribute__((ext_vector_type(4)));

__device__ __forceinline__ unsigned short bf_bits(__hip_bfloat16 h) {
    union { __hip_bfloat16 h; unsigned short u; } x; x.h = h; return x.u;
}

__device__ __forceinline__ void async_copy16(const void* gsrc, void* ldst) {
    __builtin_amdgcn_global_load_lds(
        (const __attribute__((address_space(1))) unsigned int*)gsrc,
        (__attribute__((address_space(3))) unsigned int*)ldst,
        16, 0, 0);
}

// ---------------- fp32 -> bf16 convert (8 elems/thread) ----------------
__global__ void k_f32_to_bf16(const float* __restrict__ src,
                              __hip_bfloat16* __restrict__ dst, int n8) {
    int i = blockIdx.x * blockDim.x + threadIdx.x;
    if (i >= n8) return;
    const float4* s = (const float4*)src + (size_t)i * 2;
    float4 a = s[0], b = s[1];
    union { unsigned short u[8]; uint4 v; } o;
    o.u[0] = bf_bits(__float2bfloat16(a.x));
    o.u[1] = bf_bits(__float2bfloat16(a.y));
    o.u[2] = bf_bits(__float2bfloat16(a.z));
    o.u[3] = bf_bits(__float2bfloat16(a.w));
    o.u[4] = bf_bits(__float2bfloat16(b.x));
    o.u[5] = bf_bits(__float2bfloat16(b.y));
    o.u[6] = bf_bits(__float2bfloat16(b.z));
    o.u[7] = bf_bits(__float2bfloat16(b.w));
    *((uint4*)dst + i) = o.v;
}

// ---------------- embedding gather + bf16 convert ----------------
// one thread per 8-elem chunk: 16384 rows x 64 chunks
__global__ void k_gather(const int* __restrict__ xs, const float* __restrict__ emb,
                         __hip_bfloat16* __restrict__ e_bf) {
    int tid = blockIdx.x * 256 + threadIdx.x;
    int r = tid >> 6, ch = tid & 63;
    int v = xs[r];
    const float4* s = (const float4*)(emb + (size_t)v * DE + ch * 8);
    float4 a = s[0], b = s[1];
    union { unsigned short u[8]; uint4 v4; } o;
    o.u[0] = bf_bits(__float2bfloat16(a.x));
    o.u[1] = bf_bits(__float2bfloat16(a.y));
    o.u[2] = bf_bits(__float2bfloat16(a.z));
    o.u[3] = bf_bits(__float2bfloat16(a.w));
    o.u[4] = bf_bits(__float2bfloat16(b.x));
    o.u[5] = bf_bits(__float2bfloat16(b.y));
    o.u[6] = bf_bits(__float2bfloat16(b.z));
    o.u[7] = bf_bits(__float2bfloat16(b.w));
    *((uint4*)(e_bf + (size_t)r * DE) + ch) = o.v4;
}

// ---------------- zero-init h0 (bf16) and c (fp32) ----------------
__global__ void k_zero(__hip_bfloat16* __restrict__ h0, float* __restrict__ c) {
    int i = blockIdx.x * 256 + threadIdx.x;   // 65536 threads
    c[i] = 0.0f;
    if (i < 32768) ((unsigned int*)h0)[i] = 0u;
}

// ---------------- x_gates GEMM: [16384x512] @ [4096x512]^T + bias -> bf16 ----------------
// m97-style: 128x128 tile, BK=32, 4 waves (2x2), 4x4 16x16x32 MFMA per wave
__global__ void k_gemm_xg(const __hip_bfloat16* __restrict__ A,   // [16384][512]
                          const __hip_bfloat16* __restrict__ Bt,  // [4096][512]
                          const float* __restrict__ bih, const float* __restrict__ bhh,
                          __hip_bfloat16* __restrict__ Cg) {      // [16384][4096]
    __shared__ __align__(16) __hip_bfloat16 sA[128 * 32];
    __shared__ __align__(16) __hip_bfloat16 sB[128 * 32];
    const int bm = blockIdx.x >> 5;    // 128 M-tiles
    const int bn = blockIdx.x & 31;    // 32 N-tiles
    const int tid = threadIdx.x;
    const int l = tid & 63, w = tid >> 6;
    const int wm = w >> 1, wn = w & 1;
    const int lrow = l & 15, lq = l >> 4;

    f32x4 acc[4][4] = {};

    for (int kb = 0; kb < 512; kb += 32) {
#pragma unroll
        for (int q = 0; q < 2; ++q) {
            int c = q * 256 + tid;         // 0..511 chunks of 8 bf16
            int row = c >> 2, seg = c & 3;
            async_copy16(A + (size_t)(bm * 128 + row) * 512 + kb + seg * 8, &sA[c * 8]);
            async_copy16(Bt + (size_t)(bn * 128 + row) * 512 + kb + seg * 8, &sB[c * 8]);
        }
        __syncthreads();
        bf16x8 af[4], bq[4];
#pragma unroll
        for (int mt = 0; mt < 4; ++mt)
            af[mt] = *(const bf16x8*)&sA[(wm * 64 + mt * 16 + lrow) * 32 + lq * 8];
#pragma unroll
        for (int nt = 0; nt < 4; ++nt)
            bq[nt] = *(const bf16x8*)&sB[(wn * 64 + nt * 16 + lrow) * 32 + lq * 8];
#pragma unroll
        for (int mt = 0; mt < 4; ++mt)
#pragma unroll
            for (int nt = 0; nt < 4; ++nt)
                acc[mt][nt] = __builtin_amdgcn_mfma_f32_16x16x32_bf16(
                    af[mt], bq[nt], acc[mt][nt], 0, 0, 0);
        __syncthreads();
    }

#pragma unroll
    for (int nt = 0; nt < 4; ++nt) {
        int n = bn * 128 + wn * 64 + nt * 16 + lrow;
        float bias = bih[n] + bhh[n];
#pragma unroll
        for (int mt = 0; mt < 4; ++mt) {
#pragma unroll
            for (int r = 0; r < 4; ++r) {
                int m = bm * 128 + wm * 64 + mt * 16 + lq * 4 + r;
                Cg[(size_t)m * G4 + n] = __float2bfloat16(acc[mt][nt][r] + bias);
            }
        }
    }
}

// ---------------- one LSTM timestep ----------------
// 128 blocks x 256 thr; block owns 8 hidden units (32 gate rows: 4 gates x 8 units)
// gates[64 x 32] = h_in[64 x 1024] @ Whh_sel[32 x 1024]^T  (+ xg), then cell update
__global__ void k_step(const __hip_bfloat16* __restrict__ xg,    // [T*B][4096] bf16
                       const __hip_bfloat16* __restrict__ Whh,   // [4096][1024] bf16
                       const __hip_bfloat16* __restrict__ h_in,  // [64][1024] bf16
                       __hip_bfloat16* __restrict__ h_out,       // [64][1024] bf16
                       float* __restrict__ c,                    // [64][1024] fp32
                       float* __restrict__ out,                  // d_out fp32
                       int t) {
    __shared__ __align__(16) __hip_bfloat16 sH[64 * 32];
    __shared__ __align__(16) __hip_bfloat16 sW[32 * 32];
    const int tid = threadIdx.x, l = tid & 63, w = tid >> 6;
    const int j0 = blockIdx.x * 8;
    const int lrow = l & 15, lq = l >> 4;

    f32x4 acc[2] = {};

    for (int kb = 0; kb < DH; kb += 32) {
        {   // stage h tile: 64 rows x 32 k = 256 chunks
            int ch = tid;
            int row = ch >> 2, seg = ch & 3;
            async_copy16(h_in + (size_t)row * DH + kb + seg * 8, &sH[ch * 8]);
        }
        if (tid < 128) {  // stage W tile: 32 gate rows x 32 k (waves 0,1)
            int row = tid >> 2, seg = tid & 3;
            int grow = (row >> 3) * DH + j0 + (row & 7);   // gate-major row order
            async_copy16(Whh + (size_t)grow * DH + kb + seg * 8, &sW[tid * 8]);
        }
        __syncthreads();
        bf16x8 a  = *(const bf16x8*)&sH[(w * 16 + lrow) * 32 + lq * 8];
        bf16x8 b0 = *(const bf16x8*)&sW[(lrow) * 32 + lq * 8];
        bf16x8 b1 = *(const bf16x8*)&sW[(16 + lrow) * 32 + lq * 8];
        acc[0] = __builtin_amdgcn_mfma_f32_16x16x32_bf16(a, b0, acc[0], 0, 0, 0);
        acc[1] = __builtin_amdgcn_mfma_f32_16x16x32_bf16(a, b1, acc[1], 0, 0, 0);
        __syncthreads();
    }

    // epilogue: lane holds gate cols n0=l&15 (rows 0..15 of W tile) and n1=16+(l&15)
    // W tile row order: rows 0..7 = gate-i units 0..7, rows 8..15 = gate-f units 0..7,
    //                   rows 16..23 = gate-g units 0..7, rows 24..31 = gate-o units 0..7
    const int u = l & 7;
    const int halfsel = (l >> 3) & 1;   // 0: lane has (i,g) of unit u ; 1: lane has (f,o)
    const int j = j0 + u;
#pragma unroll
    for (int r = 0; r < 4; ++r) {
        int b = w * 16 + lq * 4 + r;
        size_t rowbase = (size_t)(t * BATCH + b) * G4;
        float v0 = acc[0][r] + __bfloat162float(xg[rowbase + (size_t)halfsel * DH + j]);
        float v1 = acc[1][r] + __bfloat162float(xg[rowbase + (size_t)(2 + halfsel) * DH + j]);
        float p0 = __shfl_xor(v0, 8, 64);
        float p1 = __shfl_xor(v1, 8, 64);
        float ipre = halfsel ? p0 : v0;
        float fpre = halfsel ? v0 : p0;
        float gpre = halfsel ? p1 : v1;
        float opre = halfsel ? v1 : p1;
        if (!halfsel) {
            float ig = 1.0f / (1.0f + __expf(-ipre));
            float fg = 1.0f / (1.0f + __expf(-fpre));
            float gg = tanhf(gpre);
            float og = 1.0f / (1.0f + __expf(-opre));
            float cold = c[(size_t)b * DH + j];
            float cnew = fg * cold + ig * gg;
            float hnew = og * tanhf(cnew);
            c[(size_t)b * DH + j] = cnew;
            h_out[(size_t)b * DH + j] = __float2bfloat16(hnew);
            out[(size_t)t * BATCH * DH + (size_t)b * DH + j] = hnew;
            if (t == T_STEPS - 1) {
                out[(size_t)T_STEPS * BATCH * DH + (size_t)b * DH + j] = hnew;
                out[(size_t)T_STEPS * BATCH * DH + (size_t)BATCH * DH + (size_t)b * DH + j] = cnew;
            }
        }
    }
}

extern "C" void kernel_launch(void* const* d_in, const int* in_sizes, int n_in,
                              void* d_out, int out_size, void* d_ws, size_t ws_size,
                              hipStream_t stream) {
    const int*   xs  = (const int*)d_in[0];
    const float* emb = (const float*)d_in[1];
    const float* Wih = (const float*)d_in[2];
    const float* Whh = (const float*)d_in[3];
    const float* bih = (const float*)d_in[4];
    const float* bhh = (const float*)d_in[5];
    float* out = (float*)d_out;
    char*  ws  = (char*)d_ws;

    // workspace layout (bytes); total ~164.1 MB
    __hip_bfloat16* Wih_bf = (__hip_bfloat16*)(ws);                  //  4,194,304
    __hip_bfloat16* Whh_bf = (__hip_bfloat16*)(ws + 4194304);        //  8,388,608
    __hip_bfloat16* e_bf   = (__hip_bfloat16*)(ws + 12582912);       // 16,777,216
    __hip_bfloat16* xg     = (__hip_bfloat16*)(ws + 29360128);       // 134,217,728
    __hip_bfloat16* h0     = (__hip_bfloat16*)(ws + 163577856);      //    131,072
    __hip_bfloat16* h1     = (__hip_bfloat16*)(ws + 163708928);      //    131,072
    float*          cbuf   = (float*)(ws + 163840000);               //    262,144

    k_f32_to_bf16<<<1024, 256, 0, stream>>>(Wih, Wih_bf, 2097152 / 8);
    k_f32_to_bf16<<<2048, 256, 0, stream>>>(Whh, Whh_bf, 4194304 / 8);
    k_gather<<<4096, 256, 0, stream>>>(xs, emb, e_bf);
    k_zero<<<256, 256, 0, stream>>>(h0, cbuf);
    k_gemm_xg<<<4096, 256, 0, stream>>>(e_bf, Wih_bf, bih, bhh, xg);

    for (int t = 0; t < T_STEPS; ++t) {
        const __hip_bfloat16* hi = (t & 1) ? h1 : h0;
        __hip_bfloat16*       ho = (t & 1) ? h0 : h1;
        k_step<<<128, 256, 0, stream>>>(xg, Whh_bf, hi, ho, cbuf, out, t);
    }
}

// Round 3
// 2913.812 us; speedup vs baseline: 1.3890x; 1.3890x over previous
//
#include <hip/hip_runtime.h>
#include <hip/hip_bf16.h>
#include <cstdint>
#include <cstddef>

// LSTM encoder: T=256, B=64, VOCAB=32000, E=512, H=1024
#define T_STEPS 256
#define BATCH   64
#define DE      512
#define DH      1024
#define G4      4096   // 4*DH
#define NBLK    128    // recurrence blocks; each owns 8 hidden units

typedef short  bf16x8 __attribute__((ext_vector_type(8)));   // 8 bf16 = 4 VGPRs
typedef float  f32x4  __attribute__((ext_vector_type(4)));

__device__ __forceinline__ unsigned short bf_bits(__hip_bfloat16 h) {
    union { __hip_bfloat16 h; unsigned short u; } x; x.h = h; return x.u;
}
__device__ __forceinline__ float b2f(unsigned short u) {
    union { float f; unsigned v; } x; x.v = ((unsigned)u) << 16; return x.f;
}

__device__ __forceinline__ void async_copy16(const void* gsrc, void* ldst) {
    __builtin_amdgcn_global_load_lds(
        (const __attribute__((address_space(1))) unsigned int*)gsrc,
        (__attribute__((address_space(3))) unsigned int*)ldst,
        16, 0, 0);
}

// grid barrier: cumulative generation counter, agent-scope acq/rel
__device__ __forceinline__ void gbar(unsigned* ctr, unsigned target) {
    __syncthreads();
    if (threadIdx.x == 0) {
        __hip_atomic_fetch_add(ctr, 1u, __ATOMIC_ACQ_REL, __HIP_MEMORY_SCOPE_AGENT);
        while (__hip_atomic_load(ctr, __ATOMIC_ACQUIRE, __HIP_MEMORY_SCOPE_AGENT) < target)
            __builtin_amdgcn_s_sleep(1);
    }
    __syncthreads();
}

// ---------------- fp32 -> bf16 convert (8 elems/thread) ----------------
__global__ void k_f32_to_bf16(const float* __restrict__ src,
                              __hip_bfloat16* __restrict__ dst, int n8) {
    int i = blockIdx.x * blockDim.x + threadIdx.x;
    if (i >= n8) return;
    const float4* s = (const float4*)src + (size_t)i * 2;
    float4 a = s[0], b = s[1];
    union { unsigned short u[8]; uint4 v; } o;
    o.u[0] = bf_bits(__float2bfloat16(a.x));
    o.u[1] = bf_bits(__float2bfloat16(a.y));
    o.u[2] = bf_bits(__float2bfloat16(a.z));
    o.u[3] = bf_bits(__float2bfloat16(a.w));
    o.u[4] = bf_bits(__float2bfloat16(b.x));
    o.u[5] = bf_bits(__float2bfloat16(b.y));
    o.u[6] = bf_bits(__float2bfloat16(b.z));
    o.u[7] = bf_bits(__float2bfloat16(b.w));
    *((uint4*)dst + i) = o.v;
}

// ---------------- embedding gather + bf16 convert ----------------
__global__ void k_gather(const int* __restrict__ xs, const float* __restrict__ emb,
                         __hip_bfloat16* __restrict__ e_bf) {
    int tid = blockIdx.x * 256 + threadIdx.x;
    int r = tid >> 6, ch = tid & 63;
    int v = xs[r];
    const float4* s = (const float4*)(emb + (size_t)v * DE + ch * 8);
    float4 a = s[0], b = s[1];
    union { unsigned short u[8]; uint4 v4; } o;
    o.u[0] = bf_bits(__float2bfloat16(a.x));
    o.u[1] = bf_bits(__float2bfloat16(a.y));
    o.u[2] = bf_bits(__float2bfloat16(a.z));
    o.u[3] = bf_bits(__float2bfloat16(a.w));
    o.u[4] = bf_bits(__float2bfloat16(b.x));
    o.u[5] = bf_bits(__float2bfloat16(b.y));
    o.u[6] = bf_bits(__float2bfloat16(b.z));
    o.u[7] = bf_bits(__float2bfloat16(b.w));
    *((uint4*)(e_bf + (size_t)r * DE) + ch) = o.v4;
}

// ---------------- x_gates GEMM -> permuted bf16 layout ----------------
// xgp[t][blk][gate][unit][batch] : (((t*128+blk)*4+g)*8+u)*64 + b
__global__ void k_gemm_xg(const __hip_bfloat16* __restrict__ A,   // [16384][512]
                          const __hip_bfloat16* __restrict__ Bt,  // [4096][512]
                          const float* __restrict__ bih, const float* __restrict__ bhh,
                          __hip_bfloat16* __restrict__ xgp) {
    __shared__ __align__(16) __hip_bfloat16 sA[128 * 32];
    __shared__ __align__(16) __hip_bfloat16 sB[128 * 32];
    const int bm = blockIdx.x >> 5;    // 128 M-tiles
    const int bn = blockIdx.x & 31;    // 32 N-tiles
    const int tid = threadIdx.x;
    const int l = tid & 63, w = tid >> 6;
    const int wm = w >> 1, wn = w & 1;
    const int lrow = l & 15, lq = l >> 4;

    f32x4 acc[4][4] = {};

    for (int kb = 0; kb < 512; kb += 32) {
#pragma unroll
        for (int q = 0; q < 2; ++q) {
            int c = q * 256 + tid;
            int row = c >> 2, seg = c & 3;
            async_copy16(A + (size_t)(bm * 128 + row) * 512 + kb + seg * 8, &sA[c * 8]);
            async_copy16(Bt + (size_t)(bn * 128 + row) * 512 + kb + seg * 8, &sB[c * 8]);
        }
        __syncthreads();
        bf16x8 af[4], bq[4];
#pragma unroll
        for (int mt = 0; mt < 4; ++mt)
            af[mt] = *(const bf16x8*)&sA[(wm * 64 + mt * 16 + lrow) * 32 + lq * 8];
#pragma unroll
        for (int nt = 0; nt < 4; ++nt)
            bq[nt] = *(const bf16x8*)&sB[(wn * 64 + nt * 16 + lrow) * 32 + lq * 8];
#pragma unroll
        for (int mt = 0; mt < 4; ++mt)
#pragma unroll
            for (int nt = 0; nt < 4; ++nt)
                acc[mt][nt] = __builtin_amdgcn_mfma_f32_16x16x32_bf16(
                    af[mt], bq[nt], acc[mt][nt], 0, 0, 0);
        __syncthreads();
    }

#pragma unroll
    for (int nt = 0; nt < 4; ++nt) {
        int n = bn * 128 + wn * 64 + nt * 16 + lrow;
        int g = n >> 10, j = n & 1023, blk = j >> 3, u = j & 7;
        float bias = bih[n] + bhh[n];
#pragma unroll
        for (int mt = 0; mt < 4; ++mt) {
#pragma unroll
            for (int r = 0; r < 4; ++r) {
                int m = bm * 128 + wm * 64 + mt * 16 + lq * 4 + r;
                int t = m >> 6, b = m & 63;
                xgp[(((size_t)(t * NBLK + blk) * 4 + g) * 8 + u) * 64 + b] =
                    __float2bfloat16(acc[mt][nt][r] + bias);
            }
        }
    }
}

// ---------------- persistent LSTM recurrence ----------------
// 128 blocks x 256 thr; block owns units j0=8*bk (32 gate rows).
// Whh slice LDS-resident (64 KB, frag-contiguous); c register-resident;
// h in frag-layout global double buffer; one grid barrier per step.
__global__ void __launch_bounds__(256) k_lstm(
        const __hip_bfloat16* __restrict__ xgp,   // [256][128][4][8][64]
        const __hip_bfloat16* __restrict__ Whh,   // [4096][1024] row-major
        __hip_bfloat16* __restrict__ hbuf,        // 2 x 65536 elems, frag layout
        float* __restrict__ out,
        unsigned* __restrict__ ctr) {
    __shared__ __hip_bfloat16 sW[32768];          // 64 KB: [nt2][kb32][q4][col16][8]
    const int tid = threadIdx.x, l = tid & 63, w = tid >> 6;
    const int lrow = l & 15, lq = l >> 4;
    const int bk = blockIdx.x;

    // load Whh slice -> LDS, frag-contiguous (async: uniform base + lane*16)
#pragma unroll
    for (int f = 0; f < 16; ++f) {
        int fi = f * 256 + tid;                  // frag index 0..4095
        int col = fi & 15, q = (fi >> 4) & 3, kb = (fi >> 6) & 31, nt = fi >> 11;
        int g = (nt * 16 + col) >> 3, u = col & 7;
        async_copy16(Whh + (size_t)(g * DH + bk * 8 + u) * DH + kb * 32 + q * 8,
                     &sW[fi * 8]);
    }
    // zero my slice of h buffer 0 (elems bk*512 .. +511)
    ((unsigned*)hbuf)[bk * 256 + tid] = 0u;
    __syncthreads();                             // drains async copies too

    gbar(ctr, NBLK);                             // gen 1: h0 visible everywhere

    const int u = l & 7, halfsel = (l >> 3) & 1;
    const int b0 = w * 16 + lq * 4;
    const int aoff = (lq * 64 + w * 16 + lrow) * 8;   // A-frag elem offset per k-chunk
    float creg[4] = {0.f, 0.f, 0.f, 0.f};

    for (int t = 0; t < T_STEPS; ++t) {
        const __hip_bfloat16* hin  = hbuf + (size_t)(t & 1) * 65536;
        __hip_bfloat16*       hout = hbuf + (size_t)((t + 1) & 1) * 65536;

        // prefetch this step's xg (two 8B loads/lane)
        const __hip_bfloat16* xgt = xgp + (size_t)t * (NBLK * 2048) + (size_t)bk * 2048;
        ushort4 x0 = *(const ushort4*)(xgt + ((halfsel) * 8 + u) * 64 + b0);
        ushort4 x1 = *(const ushort4*)(xgt + ((2 + halfsel) * 8 + u) * 64 + b0);

        // K-loop: h A-frags direct from global (pipelined 8), Whh B-frags from LDS
        bf16x8 ap[8];
#pragma unroll
        for (int p = 0; p < 8; ++p)
            ap[p] = *(const bf16x8*)(hin + p * 2048 + aoff);
        f32x4 a00 = {}, a01 = {}, a10 = {}, a11 = {};
#pragma unroll
        for (int kb = 0; kb < 32; ++kb) {
            bf16x8 a  = ap[kb & 7];
            bf16x8 b0f = *(const bf16x8*)&sW[(kb * 4 + lq) * 128 + lrow * 8];
            bf16x8 b1f = *(const bf16x8*)&sW[16384 + (kb * 4 + lq) * 128 + lrow * 8];
            if (kb & 1) {
                a01 = __builtin_amdgcn_mfma_f32_16x16x32_bf16(a, b0f, a01, 0, 0, 0);
                a11 = __builtin_amdgcn_mfma_f32_16x16x32_bf16(a, b1f, a11, 0, 0, 0);
            } else {
                a00 = __builtin_amdgcn_mfma_f32_16x16x32_bf16(a, b0f, a00, 0, 0, 0);
                a10 = __builtin_amdgcn_mfma_f32_16x16x32_bf16(a, b1f, a10, 0, 0, 0);
            }
            if (kb + 8 < 32)
                ap[kb & 7] = *(const bf16x8*)(hin + (kb + 8) * 2048 + aoff);
        }
        f32x4 A0 = a00 + a01, A1 = a10 + a11;

        const unsigned short xs0[4] = {x0.x, x0.y, x0.z, x0.w};
        const unsigned short xs1[4] = {x1.x, x1.y, x1.z, x1.w};
#pragma unroll
        for (int r = 0; r < 4; ++r) {
            float v0 = A0[r] + b2f(xs0[r]);
            float v1 = A1[r] + b2f(xs1[r]);
            float p0 = __shfl_xor(v0, 8, 64);
            float p1 = __shfl_xor(v1, 8, 64);
            float ipre = halfsel ? p0 : v0;
            float fpre = halfsel ? v0 : p0;
            float gpre = halfsel ? p1 : v1;
            float opre = halfsel ? v1 : p1;
            if (!halfsel) {
                float ig = 1.0f / (1.0f + __expf(-ipre));
                float fg = 1.0f / (1.0f + __expf(-fpre));
                float gg = tanhf(gpre);
                float og = 1.0f / (1.0f + __expf(-opre));
                float cnew = fg * creg[r] + ig * gg;
                float hnew = og * tanhf(cnew);
                creg[r] = cnew;
                int b = b0 + r;
                int j = bk * 8 + u;
                hout[bk * 512 + b * 8 + u] = __float2bfloat16(hnew);
                out[(size_t)t * (BATCH * DH) + b * DH + j] = hnew;
                if (t == T_STEPS - 1) {
                    out[(size_t)T_STEPS * BATCH * DH + b * DH + j] = hnew;
                    out[(size_t)T_STEPS * BATCH * DH + BATCH * DH + b * DH + j] = cnew;
                }
            }
        }
        if (t < T_STEPS - 1)
            gbar(ctr, (unsigned)(t + 2) * NBLK);
    }
}

extern "C" void kernel_launch(void* const* d_in, const int* in_sizes, int n_in,
                              void* d_out, int out_size, void* d_ws, size_t ws_size,
                              hipStream_t stream) {
    const int*   xs  = (const int*)d_in[0];
    const float* emb = (const float*)d_in[1];
    const float* Wih = (const float*)d_in[2];
    const float* Whh = (const float*)d_in[3];
    const float* bih = (const float*)d_in[4];
    const float* bhh = (const float*)d_in[5];
    float* out = (float*)d_out;
    char*  ws  = (char*)d_ws;

    __hip_bfloat16* Wih_bf = (__hip_bfloat16*)(ws);                  //  4 MB
    __hip_bfloat16* Whh_bf = (__hip_bfloat16*)(ws + 4194304);        //  8 MB
    __hip_bfloat16* e_bf   = (__hip_bfloat16*)(ws + 12582912);       // 16 MB
    __hip_bfloat16* xgp    = (__hip_bfloat16*)(ws + 29360128);       // 128 MB
    __hip_bfloat16* hbuf   = (__hip_bfloat16*)(ws + 163577856);      // 256 KB (2 bufs)
    unsigned*       ctr    = (unsigned*)(ws + 163840000);            // 128 B

    hipMemsetAsync(ctr, 0, 128, stream);
    k_f32_to_bf16<<<1024, 256, 0, stream>>>(Wih, Wih_bf, 2097152 / 8);
    k_f32_to_bf16<<<2048, 256, 0, stream>>>(Whh, Whh_bf, 4194304 / 8);
    k_gather<<<4096, 256, 0, stream>>>(xs, emb, e_bf);
    k_gemm_xg<<<4096, 256, 0, stream>>>(e_bf, Wih_bf, bih, bhh, xgp);
    k_lstm<<<NBLK, 256, 0, stream>>>(xgp, Whh_bf, hbuf, out, ctr);
}

// Round 4
// 2239.245 us; speedup vs baseline: 1.8075x; 1.3012x over previous
//
#include <hip/hip_runtime.h>
#include <hip/hip_bf16.h>
#include <cstdint>
#include <cstddef>

// LSTM encoder: T=256, B=64, VOCAB=32000, E=512, H=1024
#define T_STEPS 256
#define BATCH   64
#define DE      512
#define DH      1024
#define G4      4096   // 4*DH
#define NBLK    128    // recurrence blocks; each owns 8 hidden units

typedef short  bf16x8 __attribute__((ext_vector_type(8)));   // 8 bf16 = 4 VGPRs
typedef float  f32x4  __attribute__((ext_vector_type(4)));
typedef unsigned long long u64;

__device__ __forceinline__ unsigned short bf_bits(__hip_bfloat16 h) {
    union { __hip_bfloat16 h; unsigned short u; } x; x.h = h; return x.u;
}
__device__ __forceinline__ float b2f(unsigned short u) {
    union { float f; unsigned v; } x; x.v = ((unsigned)u) << 16; return x.f;
}

__device__ __forceinline__ void async_copy16(const void* gsrc, void* ldst) {
    __builtin_amdgcn_global_load_lds(
        (const __attribute__((address_space(1))) unsigned int*)gsrc,
        (__attribute__((address_space(3))) unsigned int*)ldst,
        16, 0, 0);
}

// relaxed agent-scope (LLC-coherent) accessors
__device__ __forceinline__ u64 llc_load64(const u64* p) {
    return __hip_atomic_load(p, __ATOMIC_RELAXED, __HIP_MEMORY_SCOPE_AGENT);
}
__device__ __forceinline__ void llc_store64(u64* p, u64 v) {
    __hip_atomic_store(p, v, __ATOMIC_RELAXED, __HIP_MEMORY_SCOPE_AGENT);
}
__device__ __forceinline__ unsigned llc_load32(const unsigned* p) {
    return __hip_atomic_load(p, __ATOMIC_RELAXED, __HIP_MEMORY_SCOPE_AGENT);
}
__device__ __forceinline__ void llc_store32(unsigned* p, unsigned v) {
    __hip_atomic_store(p, v, __ATOMIC_RELAXED, __HIP_MEMORY_SCOPE_AGENT);
}

// ---------------- fp32 -> bf16 convert (8 elems/thread) ----------------
__global__ void k_f32_to_bf16(const float* __restrict__ src,
                              __hip_bfloat16* __restrict__ dst, int n8) {
    int i = blockIdx.x * blockDim.x + threadIdx.x;
    if (i >= n8) return;
    const float4* s = (const float4*)src + (size_t)i * 2;
    float4 a = s[0], b = s[1];
    union { unsigned short u[8]; uint4 v; } o;
    o.u[0] = bf_bits(__float2bfloat16(a.x));
    o.u[1] = bf_bits(__float2bfloat16(a.y));
    o.u[2] = bf_bits(__float2bfloat16(a.z));
    o.u[3] = bf_bits(__float2bfloat16(a.w));
    o.u[4] = bf_bits(__float2bfloat16(b.x));
    o.u[5] = bf_bits(__float2bfloat16(b.y));
    o.u[6] = bf_bits(__float2bfloat16(b.z));
    o.u[7] = bf_bits(__float2bfloat16(b.w));
    *((uint4*)dst + i) = o.v;
}

// ---------------- embedding gather + bf16 convert ----------------
__global__ void k_gather(const int* __restrict__ xs, const float* __restrict__ emb,
                         __hip_bfloat16* __restrict__ e_bf) {
    int tid = blockIdx.x * 256 + threadIdx.x;
    int r = tid >> 6, ch = tid & 63;
    int v = xs[r];
    const float4* s = (const float4*)(emb + (size_t)v * DE + ch * 8);
    float4 a = s[0], b = s[1];
    union { unsigned short u[8]; uint4 v4; } o;
    o.u[0] = bf_bits(__float2bfloat16(a.x));
    o.u[1] = bf_bits(__float2bfloat16(a.y));
    o.u[2] = bf_bits(__float2bfloat16(a.z));
    o.u[3] = bf_bits(__float2bfloat16(a.w));
    o.u[4] = bf_bits(__float2bfloat16(b.x));
    o.u[5] = bf_bits(__float2bfloat16(b.y));
    o.u[6] = bf_bits(__float2bfloat16(b.z));
    o.u[7] = bf_bits(__float2bfloat16(b.w));
    *((uint4*)(e_bf + (size_t)r * DE) + ch) = o.v4;
}

// ---------------- x_gates GEMM -> permuted bf16 layout ----------------
// xgp[t][blk][gate][unit][batch] : (((t*128+blk)*4+g)*8+u)*64 + b
__global__ void k_gemm_xg(const __hip_bfloat16* __restrict__ A,   // [16384][512]
                          const __hip_bfloat16* __restrict__ Bt,  // [4096][512]
                          const float* __restrict__ bih, const float* __restrict__ bhh,
                          __hip_bfloat16* __restrict__ xgp) {
    __shared__ __align__(16) __hip_bfloat16 sA[128 * 32];
    __shared__ __align__(16) __hip_bfloat16 sB[128 * 32];
    const int bm = blockIdx.x >> 5;    // 128 M-tiles
    const int bn = blockIdx.x & 31;    // 32 N-tiles
    const int tid = threadIdx.x;
    const int l = tid & 63, w = tid >> 6;
    const int wm = w >> 1, wn = w & 1;
    const int lrow = l & 15, lq = l >> 4;

    f32x4 acc[4][4] = {};

    for (int kb = 0; kb < 512; kb += 32) {
#pragma unroll
        for (int q = 0; q < 2; ++q) {
            int c = q * 256 + tid;
            int row = c >> 2, seg = c & 3;
            async_copy16(A + (size_t)(bm * 128 + row) * 512 + kb + seg * 8, &sA[c * 8]);
            async_copy16(Bt + (size_t)(bn * 128 + row) * 512 + kb + seg * 8, &sB[c * 8]);
        }
        __syncthreads();
        bf16x8 af[4], bq[4];
#pragma unroll
        for (int mt = 0; mt < 4; ++mt)
            af[mt] = *(const bf16x8*)&sA[(wm * 64 + mt * 16 + lrow) * 32 + lq * 8];
#pragma unroll
        for (int nt = 0; nt < 4; ++nt)
            bq[nt] = *(const bf16x8*)&sB[(wn * 64 + nt * 16 + lrow) * 32 + lq * 8];
#pragma unroll
        for (int mt = 0; mt < 4; ++mt)
#pragma unroll
            for (int nt = 0; nt < 4; ++nt)
                acc[mt][nt] = __builtin_amdgcn_mfma_f32_16x16x32_bf16(
                    af[mt], bq[nt], acc[mt][nt], 0, 0, 0);
        __syncthreads();
    }

#pragma unroll
    for (int nt = 0; nt < 4; ++nt) {
        int n = bn * 128 + wn * 64 + nt * 16 + lrow;
        int g = n >> 10, j = n & 1023, blk = j >> 3, u = j & 7;
        float bias = bih[n] + bhh[n];
#pragma unroll
        for (int mt = 0; mt < 4; ++mt) {
#pragma unroll
            for (int r = 0; r < 4; ++r) {
                int m = bm * 128 + wm * 64 + mt * 16 + lq * 4 + r;
                int t = m >> 6, b = m & 63;
                xgp[(((size_t)(t * NBLK + blk) * 4 + g) * 8 + u) * 64 + b] =
                    __float2bfloat16(acc[mt][nt][r] + bias);
            }
        }
    }
}

// ---------------- persistent LSTM recurrence ----------------
// 128 blocks x 256 thr; block owns units j0=8*bk (32 gate rows).
// Whh slice LDS-resident (64 KB); c register-resident; h exchanged through the
// LLC via relaxed agent-scope 8B atomics (sc1), triple-buffered; barrier =
// per-block flag array (no contention, no L2 writeback/invalidate).
__global__ void __launch_bounds__(256) k_lstm(
        const __hip_bfloat16* __restrict__ xgp,   // [256][128][4][8][64]
        const __hip_bfloat16* __restrict__ Whh,   // [4096][1024] row-major
        __hip_bfloat16* __restrict__ hbuf,        // 3 x 65536 elems, frag layout
        float* __restrict__ out,
        unsigned* __restrict__ flags) {           // [128], zeroed per call
    __shared__ __hip_bfloat16 sW[32768];          // 64 KB: [nt2][kb32][q4][col16][8]
    __shared__ __align__(8) __hip_bfloat16 sPack[512];
    const int tid = threadIdx.x, l = tid & 63, w = tid >> 6;
    const int lrow = l & 15, lq = l >> 4;
    const int bk = blockIdx.x;

    // load Whh slice -> LDS, frag-contiguous
#pragma unroll
    for (int f = 0; f < 16; ++f) {
        int fi = f * 256 + tid;                  // frag index 0..4095
        int col = fi & 15, q = (fi >> 4) & 3, kb = (fi >> 6) & 31, nt = fi >> 11;
        int g = (nt * 16 + col) >> 3, u = col & 7;
        async_copy16(Whh + (size_t)(g * DH + bk * 8 + u) * DH + kb * 32 + q * 8,
                     &sW[fi * 8]);
    }
    // zero my slice of h buffer 0 through the LLC
    if (tid < 128)
        llc_store64((u64*)hbuf + bk * 128 + tid, 0ull);
    asm volatile("s_waitcnt vmcnt(0)" ::: "memory");
    __syncthreads();
    if (tid == 0) llc_store32(&flags[bk], 1u);
    if (tid < 128)
        while (llc_load32(&flags[tid]) < 1u) __builtin_amdgcn_s_sleep(2);
    __syncthreads();

    const int u = l & 7, halfsel = (l >> 3) & 1;
    const int b0 = w * 16 + lq * 4;
    const int aib = lq * 128 + w * 32 + lrow * 2;   // u64 index within a k-chunk
    float creg[4] = {0.f, 0.f, 0.f, 0.f};

    for (int t = 0; t < T_STEPS; ++t) {
        const u64* hin  = (const u64*)hbuf + (size_t)(t % 3) * 16384;
        u64*       hout = (u64*)hbuf + (size_t)((t + 1) % 3) * 16384;

        // this step's xg (read-only, plain cached loads)
        const __hip_bfloat16* xgt = xgp + (size_t)t * (NBLK * 2048) + (size_t)bk * 2048;
        ushort4 x0 = *(const ushort4*)(xgt + (halfsel * 8 + u) * 64 + b0);
        ushort4 x1 = *(const ushort4*)(xgt + ((2 + halfsel) * 8 + u) * 64 + b0);

        // K-loop: h A-frags from LLC (8-deep pipeline), Whh B-frags from LDS
        u64 alo[8], ahi[8];
#pragma unroll
        for (int p = 0; p < 8; ++p) {
            alo[p] = llc_load64(hin + p * 512 + aib);
            ahi[p] = llc_load64(hin + p * 512 + aib + 1);
        }
        f32x4 a00 = {}, a01 = {}, a10 = {}, a11 = {};
#pragma unroll
        for (int kb = 0; kb < 32; ++kb) {
            union { u64 q[2]; bf16x8 v; } A;
            A.q[0] = alo[kb & 7]; A.q[1] = ahi[kb & 7];
            bf16x8 b0f = *(const bf16x8*)&sW[(kb * 4 + lq) * 128 + lrow * 8];
            bf16x8 b1f = *(const bf16x8*)&sW[16384 + (kb * 4 + lq) * 128 + lrow * 8];
            if (kb & 1) {
                a01 = __builtin_amdgcn_mfma_f32_16x16x32_bf16(A.v, b0f, a01, 0, 0, 0);
                a11 = __builtin_amdgcn_mfma_f32_16x16x32_bf16(A.v, b1f, a11, 0, 0, 0);
            } else {
                a00 = __builtin_amdgcn_mfma_f32_16x16x32_bf16(A.v, b0f, a00, 0, 0, 0);
                a10 = __builtin_amdgcn_mfma_f32_16x16x32_bf16(A.v, b1f, a10, 0, 0, 0);
            }
            if (kb + 8 < 32) {
                alo[kb & 7] = llc_load64(hin + (kb + 8) * 512 + aib);
                ahi[kb & 7] = llc_load64(hin + (kb + 8) * 512 + aib + 1);
            }
        }
        f32x4 A0 = a00 + a01, A1 = a10 + a11;

        const unsigned short xs0[4] = {x0.x, x0.y, x0.z, x0.w};
        const unsigned short xs1[4] = {x1.x, x1.y, x1.z, x1.w};
#pragma unroll
        for (int r = 0; r < 4; ++r) {
            float v0 = A0[r] + b2f(xs0[r]);
            float v1 = A1[r] + b2f(xs1[r]);
            float p0 = __shfl_xor(v0, 8, 64);
            float p1 = __shfl_xor(v1, 8, 64);
            float ipre = halfsel ? p0 : v0;
            float fpre = halfsel ? v0 : p0;
            float gpre = halfsel ? p1 : v1;
            float opre = halfsel ? v1 : p1;
            if (!halfsel) {
                float ig = 1.0f / (1.0f + __expf(-ipre));
                float fg = 1.0f / (1.0f + __expf(-fpre));
                float gg = tanhf(gpre);
                float og = 1.0f / (1.0f + __expf(-opre));
                float cnew = fg * creg[r] + ig * gg;
                float hnew = og * tanhf(cnew);
                creg[r] = cnew;
                int b = b0 + r;
                int j = bk * 8 + u;
                sPack[b * 8 + u] = __float2bfloat16(hnew);
                out[(size_t)t * (BATCH * DH) + b * DH + j] = hnew;
                if (t == T_STEPS - 1) {
                    out[(size_t)T_STEPS * BATCH * DH + b * DH + j] = hnew;
                    out[(size_t)T_STEPS * BATCH * DH + BATCH * DH + b * DH + j] = cnew;
                }
            }
        }
        __syncthreads();                         // sPack visible block-wide
        if (tid < 128)
            llc_store64(hout + bk * 128 + tid, *(const u64*)&sPack[tid * 4]);
        if (t < T_STEPS - 1) {
            asm volatile("s_waitcnt vmcnt(0)" ::: "memory");  // h at LLC before flag
            __syncthreads();                     // all waves drained
            if (tid == 0) llc_store32(&flags[bk], (unsigned)(t + 2));
            if (tid < 128)
                while (llc_load32(&flags[tid]) < (unsigned)(t + 2))
                    __builtin_amdgcn_s_sleep(2);
            __syncthreads();
        }
    }
}

extern "C" void kernel_launch(void* const* d_in, const int* in_sizes, int n_in,
                              void* d_out, int out_size, void* d_ws, size_t ws_size,
                              hipStream_t stream) {
    const int*   xs  = (const int*)d_in[0];
    const float* emb = (const float*)d_in[1];
    const float* Wih = (const float*)d_in[2];
    const float* Whh = (const float*)d_in[3];
    const float* bih = (const float*)d_in[4];
    const float* bhh = (const float*)d_in[5];
    float* out = (float*)d_out;
    char*  ws  = (char*)d_ws;

    __hip_bfloat16* Wih_bf = (__hip_bfloat16*)(ws);                  //  4 MB
    __hip_bfloat16* Whh_bf = (__hip_bfloat16*)(ws + 4194304);        //  8 MB
    __hip_bfloat16* e_bf   = (__hip_bfloat16*)(ws + 12582912);       // 16 MB
    __hip_bfloat16* xgp    = (__hip_bfloat16*)(ws + 29360128);       // 128 MB
    __hip_bfloat16* hbuf   = (__hip_bfloat16*)(ws + 163577856);      // 384 KB (3 bufs)
    unsigned*       flags  = (unsigned*)(ws + 163971072);            // 512 B

    hipMemsetAsync(flags, 0, 512, stream);
    k_f32_to_bf16<<<1024, 256, 0, stream>>>(Wih, Wih_bf, 2097152 / 8);
    k_f32_to_bf16<<<2048, 256, 0, stream>>>(Whh, Whh_bf, 4194304 / 8);
    k_gather<<<4096, 256, 0, stream>>>(xs, emb, e_bf);
    k_gemm_xg<<<4096, 256, 0, stream>>>(e_bf, Wih_bf, bih, bhh, xgp);
    k_lstm<<<NBLK, 256, 0, stream>>>(xgp, Whh_bf, hbuf, out, flags);
}